// Round 1
// baseline (72.312 us; speedup 1.0000x reference)
//
#include <hip/hip_runtime.h>
#include <math.h>

// Problem: S=4096, B=16, H=1024
//   proj[s,b,k] = sum_h enc[s,b,h]*W[k,h] + b_attn[k]
//   energies[b,s] = sum_k hidden[b,k]*proj[s,b,k]
//   out[b,0,s] = softmax_s(energies[b,s])
//
// Rewrite: energies[b,s] = v[b,:] . enc[s,b,:] + c[b]
//   where v[b,h] = sum_k hidden[b,k]*W[k,h],  c[b] = hidden[b,:].b_attn
// c[b] is constant over s -> cancels exactly in softmax (shift invariance),
// so the bias never needs to be touched (it is also zero in setup_inputs).

#define SS 4096
#define BB 16
#define HH 1024

// ---------------- Kernel A: v[b,h] = sum_k hidden[b,k] * W[k,h] ------------
// 16384 outputs, one per thread. 64 blocks x 256 threads; each block covers a
// contiguous h-range within a single b, so W reads are coalesced (1 KB/iter)
// and hidden[b,k] is block-uniform (scalar-load friendly).
__global__ void proj_hidden_kernel(const float* __restrict__ hidden,
                                   const float* __restrict__ W,
                                   float* __restrict__ v) {
    int tid = blockIdx.x * blockDim.x + threadIdx.x;   // 0..16383
    int b = tid >> 10;                                  // /H
    int h = tid & (HH - 1);
    const float* hrow = hidden + b * HH;
    float a0 = 0.f, a1 = 0.f, a2 = 0.f, a3 = 0.f;
    #pragma unroll 4
    for (int k = 0; k < HH; k += 4) {
        a0 += hrow[k + 0] * W[(k + 0) * HH + h];
        a1 += hrow[k + 1] * W[(k + 1) * HH + h];
        a2 += hrow[k + 2] * W[(k + 2) * HH + h];
        a3 += hrow[k + 3] * W[(k + 3) * HH + h];
    }
    v[tid] = (a0 + a1) + (a2 + a3);
}

// ---------------- Kernel B: energies[b,s] = v[b,:] . enc[s,b,:] ------------
// One 64-lane wave per (s,b) pair p = s*B + b (enc is [S,B,H] so the row for
// pair p starts at p*H -> perfectly contiguous). Each lane: 4x float4 loads
// (64 lanes x 16 B = 1 KB coalesced per load inst), dot with v[b,:] (64 KB
// total, L1/L2-resident), then 6-step shfl_xor reduce. Writes energy directly
// into d_out at [b*S + s] (matches output layout [B,1,S]).
__global__ void energies_kernel(const float* __restrict__ enc,
                                const float* __restrict__ v,
                                float* __restrict__ energies) {
    int p    = (blockIdx.x * blockDim.x + threadIdx.x) >> 6;  // pair index
    int lane = threadIdx.x & 63;
    int b = p & (BB - 1);
    int s = p >> 4;
    const float4* e4 = (const float4*)(enc + (size_t)p * HH);
    const float4* v4 = (const float4*)(v + b * HH);
    float acc = 0.f;
    #pragma unroll
    for (int i = 0; i < 4; ++i) {
        float4 a = e4[i * 64 + lane];
        float4 w = v4[i * 64 + lane];
        acc += a.x * w.x + a.y * w.y + a.z * w.z + a.w * w.w;
    }
    #pragma unroll
    for (int off = 32; off > 0; off >>= 1)
        acc += __shfl_xor(acc, off, 64);
    if (lane == 0) energies[b * SS + s] = acc;
}

// ---------------- Kernel C: in-place softmax over s, one block per b -------
__global__ void softmax_kernel(float* __restrict__ out) {
    int b = blockIdx.x;
    float* row = out + b * SS;
    int t = threadIdx.x;                 // 256 threads, 16 values each
    float vals[16];
    float m = -INFINITY;
    #pragma unroll
    for (int i = 0; i < 16; ++i) {
        vals[i] = row[t + i * 256];
        m = fmaxf(m, vals[i]);
    }
    #pragma unroll
    for (int off = 32; off > 0; off >>= 1)
        m = fmaxf(m, __shfl_xor(m, off, 64));
    __shared__ float redm[4];
    __shared__ float reds[4];
    int wid = t >> 6;
    if ((t & 63) == 0) redm[wid] = m;
    __syncthreads();
    m = fmaxf(fmaxf(redm[0], redm[1]), fmaxf(redm[2], redm[3]));

    float sum = 0.f;
    #pragma unroll
    for (int i = 0; i < 16; ++i) {
        vals[i] = expf(vals[i] - m);
        sum += vals[i];
    }
    #pragma unroll
    for (int off = 32; off > 0; off >>= 1)
        sum += __shfl_xor(sum, off, 64);
    if ((t & 63) == 0) reds[wid] = sum;
    __syncthreads();
    sum = reds[0] + reds[1] + reds[2] + reds[3];
    float inv = 1.0f / sum;
    #pragma unroll
    for (int i = 0; i < 16; ++i)
        row[t + i * 256] = vals[i] * inv;
}

extern "C" void kernel_launch(void* const* d_in, const int* in_sizes, int n_in,
                              void* d_out, int out_size, void* d_ws, size_t ws_size,
                              hipStream_t stream) {
    const float* hidden = (const float*)d_in[0];   // [1,B,H]
    const float* enc    = (const float*)d_in[1];   // [S,B,H]
    const float* W      = (const float*)d_in[2];   // [H,H]
    // d_in[3] = b_attn: unused (cancels in softmax; zero in setup anyway)
    float* out = (float*)d_out;                    // [B,1,S]
    float* v   = (float*)d_ws;                     // B*H floats = 64 KB

    hipLaunchKernelGGL(proj_hidden_kernel, dim3((BB * HH) / 256), dim3(256), 0, stream,
                       hidden, W, v);
    hipLaunchKernelGGL(energies_kernel, dim3((SS * BB) / 4), dim3(256), 0, stream,
                       enc, v, out);
    hipLaunchKernelGGL(softmax_kernel, dim3(BB), dim3(256), 0, stream, out);
}